// Round 8
// baseline (151.569 us; speedup 1.0000x reference)
//
#include <hip/hip_runtime.h>

#define BB 2
#define SS 2048
#define DD 1024
#define HH 16
#define HDIM 64
#define MTOT 4096  // B*S

typedef unsigned short u16;
typedef __bf16 bf16_t;
typedef bf16_t bf16x8 __attribute__((ext_vector_type(8)));
typedef u16 u16x8 __attribute__((ext_vector_type(8)));
typedef float floatx4 __attribute__((ext_vector_type(4)));
typedef float floatx16 __attribute__((ext_vector_type(16)));

__device__ __forceinline__ float bf2f(u16 u) {
  union { unsigned int i; float f; } x;
  x.i = ((unsigned int)u) << 16;
  return x.f;
}
// round-to-nearest-even f32 -> bf16 (finite inputs only)
__device__ __forceinline__ u16 f2bf(float f) {
  union { float f; unsigned int i; } x;
  x.f = f;
  unsigned int r = x.i + 0x7fffu + ((x.i >> 16) & 1u);
  return (u16)(r >> 16);
}

__device__ __forceinline__ u16x8 pack8(float4 a, float4 b) {
  u16x8 o;
  o[0] = f2bf(a.x); o[1] = f2bf(a.y); o[2] = f2bf(a.z); o[3] = f2bf(a.w);
  o[4] = f2bf(b.x); o[5] = f2bf(b.y); o[6] = f2bf(b.z); o[7] = f2bf(b.w);
  return o;
}

// ---------------- kernel 1: fused cast + QKV projection (r0 GEMM structure) ----------------
// C[m,n] = sum_k hs[m,k]*W[n,k] + bias[n], inputs fp32, outputs bf16.
// Round-8 rationale: 6 rounds of qkv pipelining grafts were neutral-to-negative
// (r0/r6 43.0/43.2; r2 48.7; r4 58.8; r5 59.4; r7 46.7) -> accept the structure, instead
// DELETE the standalone cast dispatch: stage via registers with in-flight f32->bf16
// conversion. Reg-staging enables the T14 split gload_lds cannot express:
//   cvt(pre)  ->  s_barrier  ->  ds_write  ->  issue loads(t+1)  ->  lgkmcnt(0)
//   ->  s_barrier  ->  sched_barrier  ->  ds_read frags + MFMA   (x32 K-steps)
// The t+1 global loads fly across the writes+barrier+compute phase; their vmcnt waits
// land at the NEXT iteration's cvt. Raw s_barrier (asm) avoids the compiler's
// vmcnt(0)-before-barrier drain; lgkmcnt(0)-only drain makes ds_writes block-visible.
// Inputs are f32 (hs 16.8 MB, W 3x4.2 MB); all 768 blocks co-resident share panels via
// L2/L3. Saves the cast kernel's 44 MB HBM traffic + one dispatch boundary.
#define BKK 32
__global__ __launch_bounds__(256, 2) void qkv_fused_kernel(
    const float* __restrict__ A32,
    const float* __restrict__ Wq, const float* __restrict__ Wk, const float* __restrict__ Wv,
    const float* __restrict__ bq, const float* __restrict__ bk, const float* __restrict__ bv,
    u16* __restrict__ Qo, u16* __restrict__ Ko, u16* __restrict__ Vo) {
  __shared__ u16 sA[128 * BKK];  // 8 KiB
  __shared__ u16 sB[128 * BKK];  // 8 KiB
  const int mt = blockIdx.y, ntall = blockIdx.x;
  const int seg = ntall >> 3, nt = ntall & 7;
  const float* Wp = (seg == 0) ? Wq : (seg == 1) ? Wk : Wv;
  const float* bp = (seg == 0) ? bq : (seg == 1) ? bk : bv;
  u16* Out = (seg == 0) ? Qo : (seg == 1) ? Ko : Vo;
  const int m0 = mt * 128, n0 = nt * 128;
  const int tid = threadIdx.x;
  const int lane = tid & 63, wave = tid >> 6;
  const int wm = (wave >> 1) * 64, wn = (wave & 1) * 64;
  const int l32 = lane & 31, khalf = lane >> 5;
  // staging coords (r0 shape): rows srow0, srow0+16; 8 elements starting at scol.
  const int srow0 = wave * 32 + (lane >> 2);
  const int scol = (lane & 3) * 8;
  const float* pa0 = A32 + (size_t)(m0 + srow0) * DD + scol;
  const float* pa1 = A32 + (size_t)(m0 + srow0 + 16) * DD + scol;
  const float* pw0 = Wp + (size_t)(n0 + srow0) * DD + scol;
  const float* pw1 = Wp + (size_t)(n0 + srow0 + 16) * DD + scol;

  float4 pre[8];
  // prologue: loads for tile 0
  pre[0] = *reinterpret_cast<const float4*>(pa0);
  pre[1] = *reinterpret_cast<const float4*>(pa0 + 4);
  pre[2] = *reinterpret_cast<const float4*>(pa1);
  pre[3] = *reinterpret_cast<const float4*>(pa1 + 4);
  pre[4] = *reinterpret_cast<const float4*>(pw0);
  pre[5] = *reinterpret_cast<const float4*>(pw0 + 4);
  pre[6] = *reinterpret_cast<const float4*>(pw1);
  pre[7] = *reinterpret_cast<const float4*>(pw1 + 4);

  floatx16 acc[2][2] = {};
  for (int t = 0; t < 32; ++t) {
    // convert the in-register tile (vmcnt waits for pre[] resolve here; for t>0 those
    // loads were issued a full compute-phase ago)
    u16x8 wa0 = pack8(pre[0], pre[1]);
    u16x8 wa1 = pack8(pre[2], pre[3]);
    u16x8 wb0 = pack8(pre[4], pre[5]);
    u16x8 wb1 = pack8(pre[6], pre[7]);
    // barrier: all waves' ds_reads of the previous tile are retired (their data was
    // consumed by MFMAs before each wave arrived here) -> safe to overwrite LDS
    asm volatile("s_barrier" ::: "memory");
    *reinterpret_cast<u16x8*>(sA + srow0 * BKK + scol) = wa0;
    *reinterpret_cast<u16x8*>(sA + (srow0 + 16) * BKK + scol) = wa1;
    *reinterpret_cast<u16x8*>(sB + srow0 * BKK + scol) = wb0;
    *reinterpret_cast<u16x8*>(sB + (srow0 + 16) * BKK + scol) = wb1;
    // issue next tile's global loads NOW: they fly across lgkm-drain + barrier + MFMA phase
    if (t < 31) {
      const int k1 = (t + 1) * BKK;
      pre[0] = *reinterpret_cast<const float4*>(pa0 + k1);
      pre[1] = *reinterpret_cast<const float4*>(pa0 + k1 + 4);
      pre[2] = *reinterpret_cast<const float4*>(pa1 + k1);
      pre[3] = *reinterpret_cast<const float4*>(pa1 + k1 + 4);
      pre[4] = *reinterpret_cast<const float4*>(pw0 + k1);
      pre[5] = *reinterpret_cast<const float4*>(pw0 + k1 + 4);
      pre[6] = *reinterpret_cast<const float4*>(pw1 + k1);
      pre[7] = *reinterpret_cast<const float4*>(pw1 + k1 + 4);
    }
    // drain ONLY LDS writes (not the vmcnt prefetch), then block-wide visibility
    asm volatile("s_waitcnt lgkmcnt(0)" ::: "memory");
    asm volatile("s_barrier" ::: "memory");
    __builtin_amdgcn_sched_barrier(0);  // rule #18: pin compute below the wait+barrier
    // compute (exact r0 body)
#pragma unroll
    for (int kk = 0; kk < 2; ++kk) {
      bf16x8 af[2], bfr[2];
#pragma unroll
      for (int i = 0; i < 2; ++i)
        af[i] = *reinterpret_cast<const bf16x8*>(sA + (wm + i * 32 + l32) * BKK + kk * 16 + khalf * 8);
#pragma unroll
      for (int j = 0; j < 2; ++j)
        bfr[j] = *reinterpret_cast<const bf16x8*>(sB + (wn + j * 32 + l32) * BKK + kk * 16 + khalf * 8);
#pragma unroll
      for (int i = 0; i < 2; ++i)
#pragma unroll
        for (int j = 0; j < 2; ++j)
          acc[i][j] = __builtin_amdgcn_mfma_f32_32x32x16_bf16(af[i], bfr[j], acc[i][j], 0, 0, 0);
    }
  }

  // epilogue: C/D layout col=lane&31, row=(reg&3)+8*(reg>>2)+4*(lane>>5)
#pragma unroll
  for (int j = 0; j < 2; ++j) {
    int col = n0 + wn + j * 32 + l32;
    float bias = bp[col];
#pragma unroll
    for (int i = 0; i < 2; ++i) {
#pragma unroll
      for (int reg = 0; reg < 16; ++reg) {
        int row = m0 + wm + i * 32 + (reg & 3) + 8 * (reg >> 2) + 4 * khalf;
        Out[(size_t)row * DD + col] = f2bf(acc[i][j][reg] + bias);
      }
    }
  }
}

// ---------------- kernel 2: mpart[pc][bh][d][e] = sum_{s in chunk pc} mask[s]*V[s,d]*K[s,e] ----------------
// 8 superchunks of 256 s-rows (4 sub-tiles of 64) x 32 bh = 256 blocks (r0-proven shape).
__global__ __launch_bounds__(256) void m_partial_kernel(
    const u16* __restrict__ Xb, const u16* __restrict__ Yb,
    const float* __restrict__ am, float* __restrict__ mpart) {
  __shared__ float sX[64 * 68];
  __shared__ float sY[64 * 68];
  const int bh = blockIdx.y;     // 0..31
  const int b = bh >> 4, h = bh & 15;
  const int tid = threadIdx.x;
  const int e0 = (tid & 15) * 4, d0 = (tid >> 4) * 4;
  float acc[4][4] = {};
  for (int cs = 0; cs < 4; ++cs) {
    const int s0 = (blockIdx.x * 4 + cs) * 64;
    if (cs) __syncthreads();  // protect LDS before restage
#pragma unroll
    for (int c = 0; c < 2; ++c) {
      int L = tid + c * 256;
      int srow = L >> 3;            // 0..63
      int col = (L & 7) * 8;        // 0..56
      size_t g = (size_t)(b * SS + s0 + srow) * DD + h * HDIM + col;
      uint4 xraw = *reinterpret_cast<const uint4*>(Xb + g);
      uint4 yraw = *reinterpret_cast<const uint4*>(Yb + g);
      float m = (am[b * SS + s0 + srow] >= 0.f) ? 1.f : 0.f;
      unsigned int xw[4] = {xraw.x, xraw.y, xraw.z, xraw.w};
      unsigned int yw[4] = {yraw.x, yraw.y, yraw.z, yraw.w};
#pragma unroll
      for (int q = 0; q < 4; ++q) {
        sX[srow * 68 + col + 2 * q]     = m * bf2f((u16)(xw[q] & 0xffffu));
        sX[srow * 68 + col + 2 * q + 1] = m * bf2f((u16)(xw[q] >> 16));
        sY[srow * 68 + col + 2 * q]     = bf2f((u16)(yw[q] & 0xffffu));
        sY[srow * 68 + col + 2 * q + 1] = bf2f((u16)(yw[q] >> 16));
      }
    }
    __syncthreads();
    for (int s = 0; s < 64; ++s) {
      float4 xx = *reinterpret_cast<const float4*>(&sX[s * 68 + e0]);
      float4 yy = *reinterpret_cast<const float4*>(&sY[s * 68 + d0]);
      float xa[4] = {xx.x, xx.y, xx.z, xx.w};
      float ya[4] = {yy.x, yy.y, yy.z, yy.w};
#pragma unroll
      for (int i = 0; i < 4; ++i)
#pragma unroll
        for (int j = 0; j < 4; ++j) acc[i][j] += xa[i] * ya[j];
    }
  }
  float* outp = mpart + ((size_t)(blockIdx.x * 32 + bh)) * 4096;
#pragma unroll
  for (int i = 0; i < 4; ++i) {
    float4 o = {acc[i][0], acc[i][1], acc[i][2], acc[i][3]};
    *reinterpret_cast<float4*>(&outp[(e0 + i) * 64 + d0]) = o;
  }
}

// ---------------- kernel 3: ctx[m, h*64+d] = sum_e Q[m, h*64+e] * M[e,d]  (MFMA) ----------------
// Inline 8-partial reduction during M staging (mpart 4 MB, L2-resident).
__global__ __launch_bounds__(256) void ctx_kernel(
    const u16* __restrict__ Qb, const float* __restrict__ mpart, float* __restrict__ Out) {
  __shared__ u16 sMT[64 * 72];
  const int m0 = blockIdx.x * 128;
  const int h = blockIdx.y;
  const int b = m0 >> 11;         // 128-row tiles never cross the batch boundary
  const int bh = b * HH + h;
  const int tid = threadIdx.x;
#pragma unroll
  for (int c = 0; c < 4; ++c) {
    int L4 = c * 256 + tid;       // float4 index 0..1023 within the 64x64 M^T block
    float4 s = {0.f, 0.f, 0.f, 0.f};
#pragma unroll
    for (int pc = 0; pc < 8; ++pc) {
      const float4* p4 = reinterpret_cast<const float4*>(mpart + ((size_t)(pc * 32 + bh)) * 4096);
      float4 t = p4[L4];
      s.x += t.x; s.y += t.y; s.z += t.z; s.w += t.w;
    }
    int d = L4 >> 4, e = (L4 & 15) * 4;
    ushort4 o = {f2bf(s.x), f2bf(s.y), f2bf(s.z), f2bf(s.w)};
    *reinterpret_cast<ushort4*>(&sMT[d * 72 + e]) = o;
  }
  __syncthreads();
  const int lane = tid & 63, wave = tid >> 6;
  const int l32 = lane & 31, khalf = lane >> 5;
  const int arow = m0 + wave * 32 + l32;
  const u16* qrow = Qb + (size_t)arow * DD + h * HDIM + khalf * 8;
  bf16x8 af[4], bfr[2][4];
#pragma unroll
  for (int k0 = 0; k0 < 4; ++k0) {
    af[k0] = *reinterpret_cast<const bf16x8*>(qrow + k0 * 16);
#pragma unroll
    for (int j = 0; j < 2; ++j)
      bfr[j][k0] = *reinterpret_cast<const bf16x8*>(
          &sMT[(j * 32 + l32) * 72 + k0 * 16 + khalf * 8]);
  }
  floatx16 acc[2] = {};
#pragma unroll
  for (int j = 0; j < 2; ++j)
#pragma unroll
    for (int k0 = 0; k0 < 4; ++k0)
      acc[j] = __builtin_amdgcn_mfma_f32_32x32x16_bf16(af[k0], bfr[j][k0], acc[j], 0, 0, 0);
  // C/D layout: col = lane&31, row = (reg&3)+8*(reg>>2)+4*khalf
#pragma unroll
  for (int j = 0; j < 2; ++j) {
    int col = h * HDIM + j * 32 + l32;
#pragma unroll
    for (int reg = 0; reg < 16; ++reg) {
      int r = m0 + wave * 32 + (reg & 3) + 8 * (reg >> 2) + 4 * khalf;
      Out[(size_t)r * DD + col] = acc[j][reg];
    }
  }
}

extern "C" void kernel_launch(void* const* d_in, const int* in_sizes, int n_in,
                              void* d_out, int out_size, void* d_ws, size_t ws_size,
                              hipStream_t stream) {
  const float* hs = (const float*)d_in[0];
  const float* am = (const float*)d_in[1];
  const float* wq = (const float*)d_in[2];
  const float* bq = (const float*)d_in[3];
  const float* wk = (const float*)d_in[4];
  const float* bk = (const float*)d_in[5];
  const float* wv = (const float*)d_in[6];
  const float* bv = (const float*)d_in[7];
  float* out = (float*)d_out;
  char* ws = (char*)d_ws;

  // workspace layout (bytes), all 16B-aligned; total 28 MiB (hs_b/w*_b eliminated)
  u16* q_b  = (u16*)(ws);                  // 8 MiB [4096,1024] bf16
  u16* k_b  = (u16*)(ws + 8388608);        // 8 MiB
  u16* v_b  = (u16*)(ws + 16777216);       // 8 MiB
  float* mpart = (float*)(ws + 25165824);  // 4 MiB [8 pc][32 bh][64][64] f32 (M^T partials)

  qkv_fused_kernel<<<dim3(24, 32), 256, 0, stream>>>(hs, wq, wk, wv,
                                                     bq, bk, bv, q_b, k_b, v_b);
  // X=V, Y=K -> partials hold M^T
  m_partial_kernel<<<dim3(8, 32), 256, 0, stream>>>(v_b, k_b, am, mpart);
  ctx_kernel<<<dim3(32, 16), 256, 0, stream>>>(q_b, mpart, out);
}